// Round 7
// baseline (109.385 us; speedup 1.0000x reference)
//
#include <hip/hip_runtime.h>

// RoIAlign forward (SR=2, aligned). feat [4,256,100,100] f32, rois [512,5], out [512,256,7,7].
// PIPELINED: block = (roi, 32ch) = 8 items x 4ch. Double-buffered LDS patch;
// staging by global_load_lds DMA (width 16; unpadded PSTR=28 makes the LDS
// dest exactly wave-base + lane*16). Loop: DMA(i+1) -> compute(i) -> barrier
// (its vmcnt(0) drain IS the pipeline wait). Geometry amortized over 8 items.

#define FEAT_C 256
#define FEAT_H 100
#define FEAT_W 100
#define HW     10000
#define NROI   512
#define NBINS  49
#define CPI    4                        // channels per item
#define ITEMS  8                        // items per block (32 channels)
#define PROWS  25                       // max patch rows (floor-span<=23, +2)
#define PSTR   28                       // dwords/row, UNPADDED: task id*16B = LDS offset
#define CBYTES (PROWS * PSTR * 4)       // 2800 B per channel
#define BUFDW  (CPI * PROWS * PSTR)     // 2800 dwords per buffer
#define BUFBYTES (BUFDW * 4)            // 11200 B

// Matches ref: v=max(v,0); l=floor(v) clamped at 99; fr=v-l_clamped.
__device__ __forceinline__ void samp_geo(float s, float bsz, int idx, int sr_i,
                                         int& lo, float& fr) {
    float v = s + bsz * ((float)idx + ((float)sr_i + 0.5f) * 0.5f);
    v = fmaxf(v, 0.0f);
    int l = (int)v;                     // v>=0: trunc == floor == astype(int32)
    if (l > FEAT_H - 1) l = FEAT_H - 1; // H == W == 100
    fr = v - (float)l;
    lo = l;
}

__global__ __launch_bounds__(256, 7) void roialign_fwd(
    const float* __restrict__ feat,
    const float* __restrict__ rois,
    float* __restrict__ out)
{
    __shared__ __align__(16) float s_patch[2 * BUFDW];   // 22400 B
    __shared__ __align__(16) int2  s_yt[14];  // {patch row byte-off, bits(fry)}
    __shared__ __align__(16) int2  s_xt[14];  // {patch x byte-off, bits(frx')}

    const int bid  = blockIdx.x;
    const int k    = bid >> 3;                // roi
    const int cgrp = bid & 7;                 // 32-channel group
    const int tid  = threadIdx.x;

    const float* r = rois + k * 5;            // k uniform -> scalar loads
    const int   b  = (int)r[0];
    const float sw = r[1] * 0.25f - 0.5f, sh = r[2] * 0.25f - 0.5f;
    const float ew = r[3] * 0.25f - 0.5f, eh = r[4] * 0.25f - 0.5f;
    const float bh = (eh - sh) * (1.0f / 7.0f);
    const float bw = (ew - sw) * (1.0f / 7.0f);

    // Bounds: bit-identical expressions in every thread.
    int y0, yM, x0, xM; float fd;
    samp_geo(sh, bh, 0, 0, y0, fd);  samp_geo(sh, bh, 6, 1, yM, fd);
    samp_geo(sw, bw, 0, 0, x0, fd);  samp_geo(sw, bw, 6, 1, xM, fd);
    const int ax0  = x0 & ~3;                 // 16B-aligned x origin (<=96)
    const int rows = yM - y0 + 2;             // <= 25

    // Geometry tables, once per block (wave 0), before the prologue barrier.
    if (tid < 14) {
        int lo; float fr;
        samp_geo(sh, bh, tid >> 1, tid & 1, lo, fr);
        s_yt[tid] = make_int2((lo - y0) * (PSTR * 4), __float_as_int(fr));
    } else if (tid >= 32 && tid < 46) {
        int t = tid - 32; int lo; float fr;
        samp_geo(sw, bw, t >> 1, t & 1, lo, fr);
        if (lo >= FEAT_W - 1) fr = 0.0f;      // x border: xh==xl -> kill hi weight
        s_xt[t] = make_int2((lo - ax0) * 4, __float_as_int(fr));
    }

    // Staging lane constants: task tid = py*7 + q covers patch row py, quad q.
    const int  spy = (tid * 9363) >> 16;      // tid/7 (exact for tid<256)
    const int  sq  = tid - spy * 7;
    int sy = y0 + spy; if (sy > FEAT_H - 1) sy = FEAT_H - 1;   // bottom dup row
    int sc = ax0 + sq * 4; if (sc > FEAT_W - 4) sc = FEAT_W - 4; // clamped quads
    const int  goff   = sy * FEAT_W + sc;     // dword off in channel (16B-aligned)
    const bool stager = tid < rows * 7;       // <= 175 lanes
    const int  wid    = __builtin_amdgcn_readfirstlane(tid >> 6);
    const float* fblk = feat + (size_t)(b * FEAT_C + cgrp * 32) * HW;

    auto dma = [&](int item, int selb) {
        if (stager) {
            const float* g0 = fblk + (size_t)item * (CPI * HW) + goff;
            char* l0 = (char*)s_patch + selb * BUFBYTES + wid * 1024;
            #pragma unroll
            for (int c = 0; c < CPI; c++)
                __builtin_amdgcn_global_load_lds(
                    (const __attribute__((address_space(1))) void*)(g0 + c * HW),
                    (__attribute__((address_space(3))) void*)(l0 + c * CBYTES),
                    16, 0, 0);
        }
    };

    // ---- Prologue: stage item 0, then one barrier (drains DMA, publishes geo).
    dma(0, 0);
    __syncthreads();

    // Compute-thread constants (tid < 196): (channel, bin) + geometry in regs.
    const int cch  = (tid * 335) >> 14;       // tid/49 (exact for tid<196)
    const int cbin = tid - cch * 49;
    const int cph  = (cbin * 37) >> 8;        // bin/7 (exact for bin<49)
    const int cpw  = cbin - cph * 7;
    const int4 yg = *(const int4*)&s_yt[2 * cph];   // {offA,fryA, offB,fryB}
    const int4 xg = *(const int4*)&s_xt[2 * cpw];   // {off0,frx0, off1,frx1}
    const float lyA = __int_as_float(yg.y), hyA = 1.0f - lyA;
    const float lyB = __int_as_float(yg.w), hyB = 1.0f - lyB;
    const float lx0 = __int_as_float(xg.y), hx0 = 1.0f - lx0;
    const float lx1 = __int_as_float(xg.w), hx1 = 1.0f - lx1;
    const int   choff = cch * CBYTES;
    float* const oblk = out + (size_t)(k * FEAT_C + cgrp * 32) * NBINS;

    int sel = 0;
    #pragma unroll
    for (int i = 0; i < ITEMS; i++) {
        if (i < ITEMS - 1) dma(i + 1, sel ^ 1);   // in flight during compute(i)

        if (tid < CPI * NBINS) {
            const char* cb  = (const char*)s_patch + sel * BUFBYTES + choff;
            const char* rA  = cb + yg.x;          // y-sample A, low row
            const char* rB  = cb + yg.z;          // y-sample B, low row
            // 8 adjacent-pair LDS reads (ds_read2_b32) + bilinear FMA.
            const float* a00 = (const float*)(rA + xg.x);
            const float* a01 = (const float*)(rA + xg.z);
            const float* a10 = (const float*)(rA + PSTR * 4 + xg.x);
            const float* a11 = (const float*)(rA + PSTR * 4 + xg.z);
            const float* b00 = (const float*)(rB + xg.x);
            const float* b01 = (const float*)(rB + xg.z);
            const float* b10 = (const float*)(rB + PSTR * 4 + xg.x);
            const float* b11 = (const float*)(rB + PSTR * 4 + xg.z);
            float loA = hx0 * a00[0] + lx0 * a00[1] + hx1 * a01[0] + lx1 * a01[1];
            float hiA = hx0 * a10[0] + lx0 * a10[1] + hx1 * a11[0] + lx1 * a11[1];
            float loB = hx0 * b00[0] + lx0 * b00[1] + hx1 * b01[0] + lx1 * b01[1];
            float hiB = hx0 * b10[0] + lx0 * b10[1] + hx1 * b11[0] + lx1 * b11[1];
            float acc = hyA * loA + lyA * hiA + hyB * loB + lyB * hiB;
            oblk[i * (CPI * NBINS) + tid] = acc * 0.25f;   // / (SR*SR), coalesced
        }

        if (i < ITEMS - 1) __syncthreads();   // drains DMA(i+1) = the pipeline wait;
        sel ^= 1;                              // also fences buf reuse.
    }
}

extern "C" void kernel_launch(void* const* d_in, const int* in_sizes, int n_in,
                              void* d_out, int out_size, void* d_ws, size_t ws_size,
                              hipStream_t stream) {
    const float* feat = (const float*)d_in[0];
    const float* rois = (const float*)d_in[1];
    float*       outp = (float*)d_out;
    // 512 rois x 8 channel-groups(32ch) = 4096 blocks x 256 threads.
    roialign_fwd<<<dim3(NROI * 8), dim3(256), 0, stream>>>(feat, rois, outp);
}

// Round 8
// 102.629 us; speedup vs baseline: 1.0658x; 1.0658x over previous
//
#include <hip/hip_runtime.h>

// RoIAlign forward (SR=2, aligned). feat [4,256,100,100] f32, rois [512,5], out [512,256,7,7].
// INVERTED decomposition: block = (image, channel). The whole 100x100 channel
// plane (40 KB) is DMA'd into LDS once with coalesced 1KB chunks (no scattered
// patch staging). A setup kernel precomputes per-(roi,bin) 32B records
// (packed LDS byte-offsets + bilinear weights + output index) into d_ws,
// grouped by image. Main loop streams records with all 64 lanes active:
// 8 ds_read2_b32 + ~24 FMA per output, records software-prefetched.

#define FEAT_C 256
#define FEAT_H 100
#define FEAT_W 100
#define HW     10000
#define NROI   512
#define NBINS  49
#define IMG_N  4

#define REC_BYTES  32
#define IMG_STRIDE (NROI * NBINS * REC_BYTES)   // worst case: all rois in one image
#define CNT_OFF    (IMG_N * IMG_STRIDE)         // counts[4] after record area

// Matches ref: v=max(v,0); l=floor(v) clamped at 99; fr=v-l_clamped.
__device__ __forceinline__ void samp_geo(float s, float bsz, int idx, int sr_i,
                                         int& lo, float& fr) {
    float v = s + bsz * ((float)idx + ((float)sr_i + 0.5f) * 0.5f);
    v = fmaxf(v, 0.0f);
    int l = (int)v;                   // v>=0: trunc == floor == astype(int32)
    if (l > FEAT_H - 1) l = FEAT_H - 1;
    fr = v - (float)l;
    lo = l;
}

// ---- Setup: one block per roi; ballot-computed per-image slot (no atomics).
__global__ __launch_bounds__(64) void roialign_setup(
    const float* __restrict__ rois, char* __restrict__ ws)
{
    const int k    = blockIdx.x;
    const int lane = threadIdx.x;
    const float* r = rois + k * 5;
    const int bk   = (int)r[0];

    // slot = #{j<k : img(j)==img(k)}; total = #{j : img(j)==img(k)}
    int slot = 0, total = 0;
    for (int i = 0; i < NROI; i += 64) {
        int bi = (int)rois[(i + lane) * 5];
        unsigned long long m = __ballot(bi == bk);
        total += __popcll(m);
        int rel = k - i;
        unsigned long long lt = rel <= 0 ? 0ull
                              : (rel >= 64 ? ~0ull : ((1ull << rel) - 1ull));
        slot += __popcll(m & lt);
    }
    if (lane == 0) ((int*)(ws + CNT_OFF))[bk] = total;   // redundant same-value writes

    if (lane < NBINS) {
        const float sw = r[1] * 0.25f - 0.5f, sh = r[2] * 0.25f - 0.5f;
        const float ew = r[3] * 0.25f - 0.5f, eh = r[4] * 0.25f - 0.5f;
        const float bh = (eh - sh) * (1.0f / 7.0f);
        const float bw = (ew - sw) * (1.0f / 7.0f);
        const int ph = (lane * 37) >> 8;        // lane/7 (exact, lane<49)
        const int pw = lane - ph * 7;
        int ylA, ylB, xl0, xl1; float lyA, lyB, lx0, lx1;
        samp_geo(sh, bh, ph, 0, ylA, lyA);
        samp_geo(sh, bh, ph, 1, ylB, lyB);
        samp_geo(sw, bw, pw, 0, xl0, lx0);
        samp_geo(sw, bw, pw, 1, xl1, lx1);
        if (xl0 >= FEAT_W - 1) lx0 = 0.0f;      // x border: xh==xl -> kill hi weight
        if (xl1 >= FEAT_W - 1) lx1 = 0.0f;      //   (OOB dword lands in zeroed pad)
        int yhA = min(ylA + 1, FEAT_H - 1), yhB = min(ylB + 1, FEAT_H - 1);
        uint4 a, b2;
        a.x  = (unsigned)(ylA * 400) | ((unsigned)(yhA * 400) << 16);  // row byte-offs
        a.y  = (unsigned)(ylB * 400) | ((unsigned)(yhB * 400) << 16);
        a.z  = (unsigned)(xl0 * 4)   | ((unsigned)(xl1 * 4)   << 16);  // col byte-offs
        a.w  = __float_as_uint(lyA);
        b2.x = __float_as_uint(lyB);
        b2.y = __float_as_uint(lx0);
        b2.z = __float_as_uint(lx1);
        b2.w = (unsigned)(k * (FEAT_C * NBINS) + lane);  // out dword idx (roi+bin part)
        char* dst = ws + bk * IMG_STRIDE + (slot * NBINS + lane) * REC_BYTES;
        *(uint4*)dst        = a;
        *(uint4*)(dst + 16) = b2;
    }
}

// ---- Main: block = (img, channel); channel plane resident in LDS.
__global__ __launch_bounds__(256) void roialign_main(
    const float* __restrict__ feat, const char* __restrict__ ws,
    float* __restrict__ out)
{
    __shared__ __align__(16) float s_img[HW + 4];        // 40016 B -> 4 blocks/CU

    const int bid  = blockIdx.x;
    const int img  = bid & 3;
    const int c    = bid >> 2;
    const int tid  = threadIdx.x;
    const int lane = tid & 63;
    const int w    = __builtin_amdgcn_readfirstlane(tid >> 6);

    // Stage the channel plane: 40 coalesced 1KB DMA chunks (4 waves x 10).
    const char* src = (const char*)(feat + (size_t)(img * FEAT_C + c) * HW);
    for (int j = w; j < 40; j += 4) {
        int off = j * 1024 + lane * 16;
        if (off < HW * 4)
            __builtin_amdgcn_global_load_lds(
                (const __attribute__((address_space(1))) void*)(src + off),
                (__attribute__((address_space(3))) void*)((char*)s_img + off),
                16, 0, 0);
    }
    if (tid < 4) s_img[HW + tid] = 0.0f;        // pad: zero-weight border tap target

    const int   nrec = ((const int*)(ws + CNT_OFF))[img] * NBINS;
    const char* rb   = ws + img * IMG_STRIDE;
    float* const oc  = out + (size_t)c * NBINS; // + rec's out idx = final address

    // Prefetch record 0 while DMA is in flight.
    int   idx = tid;
    uint4 ra, rbk;
    if (idx < nrec) {
        const char* p = rb + idx * REC_BYTES;
        ra  = *(const uint4*)p;
        rbk = *(const uint4*)(p + 16);
    }
    __syncthreads();                            // drains DMA (and rec loads)

    while (idx < nrec) {
        const uint4 a = ra, b2 = rbk;
        const int nidx = idx + 256;
        if (nidx < nrec) {                      // prefetch next record
            const char* p = rb + nidx * REC_BYTES;
            ra  = *(const uint4*)p;
            rbk = *(const uint4*)(p + 16);
        }

        const char* base = (const char*)s_img;
        const int oAl = a.x & 0xffff, oAh = a.x >> 16;
        const int oBl = a.y & 0xffff, oBh = a.y >> 16;
        const int x0  = a.z & 0xffff, x1  = a.z >> 16;
        const float lyA = __uint_as_float(a.w),  hyA = 1.0f - lyA;
        const float lyB = __uint_as_float(b2.x), hyB = 1.0f - lyB;
        const float lx0 = __uint_as_float(b2.y), hx0 = 1.0f - lx0;
        const float lx1 = __uint_as_float(b2.z), hx1 = 1.0f - lx1;

        // 8 adjacent-pair LDS reads (ds_read2_b32 offset0:0 offset1:1).
        const float* pAl0 = (const float*)(base + oAl + x0);
        const float* pAl1 = (const float*)(base + oAl + x1);
        const float* pAh0 = (const float*)(base + oAh + x0);
        const float* pAh1 = (const float*)(base + oAh + x1);
        const float* pBl0 = (const float*)(base + oBl + x0);
        const float* pBl1 = (const float*)(base + oBl + x1);
        const float* pBh0 = (const float*)(base + oBh + x0);
        const float* pBh1 = (const float*)(base + oBh + x1);

        float sAl = hx0 * pAl0[0] + lx0 * pAl0[1] + hx1 * pAl1[0] + lx1 * pAl1[1];
        float sAh = hx0 * pAh0[0] + lx0 * pAh0[1] + hx1 * pAh1[0] + lx1 * pAh1[1];
        float sBl = hx0 * pBl0[0] + lx0 * pBl0[1] + hx1 * pBl1[0] + lx1 * pBl1[1];
        float sBh = hx0 * pBh0[0] + lx0 * pBh0[1] + hx1 * pBh1[0] + lx1 * pBh1[1];
        float acc = hyA * sAl + lyA * sAh + hyB * sBl + lyB * sBh;

        oc[b2.w] = acc * 0.25f;                 // / (SR*SR)
        idx = nidx;
    }
}

extern "C" void kernel_launch(void* const* d_in, const int* in_sizes, int n_in,
                              void* d_out, int out_size, void* d_ws, size_t ws_size,
                              hipStream_t stream) {
    const float* feat = (const float*)d_in[0];
    const float* rois = (const float*)d_in[1];
    float*       outp = (float*)d_out;
    roialign_setup<<<dim3(NROI), dim3(64), 0, stream>>>(rois, (char*)d_ws);
    roialign_main<<<dim3(IMG_N * FEAT_C), dim3(256), 0, stream>>>(
        feat, (const char*)d_ws, outp);
}

// Round 9
// 100.814 us; speedup vs baseline: 1.0850x; 1.0180x over previous
//
#include <hip/hip_runtime.h>

// RoIAlign forward (SR=2, aligned). feat [4,256,100,100] f32, rois [512,5], out [512,256,7,7].
// Block = (image, CHANNEL PAIR). The two 100x100 planes are staged INTERLEAVED
// (float2 per pixel, 80 KB LDS) so every record tap is one ds_read2_b64
// serving both channels -> LDS instructions, record loads and VALU per output
// all ~halve vs the single-channel version. Setup kernel precomputes
// per-(roi,bin) 32B records (offsets+weights+out index) grouped by image.

#define FEAT_C 256
#define FEAT_H 100
#define FEAT_W 100
#define HW     10000
#define NROI   512
#define NBINS  49
#define IMG_N  4

#define REC_BYTES  32
#define IMG_STRIDE (NROI * NBINS * REC_BYTES)   // worst case: all rois in one image
#define CNT_OFF    (IMG_N * IMG_STRIDE)         // counts[4] after record area

typedef float f32x2 __attribute__((ext_vector_type(2)));

// Matches ref: v=max(v,0); l=floor(v) clamped at 99; fr=v-l_clamped.
__device__ __forceinline__ void samp_geo(float s, float bsz, int idx, int sr_i,
                                         int& lo, float& fr) {
    float v = s + bsz * ((float)idx + ((float)sr_i + 0.5f) * 0.5f);
    v = fmaxf(v, 0.0f);
    int l = (int)v;                   // v>=0: trunc == floor == astype(int32)
    if (l > FEAT_H - 1) l = FEAT_H - 1;
    fr = v - (float)l;
    lo = l;
}

// ---- Setup: one block per roi; ballot-computed per-image slot (no atomics).
__global__ __launch_bounds__(64) void roialign_setup(
    const float* __restrict__ rois, char* __restrict__ ws)
{
    const int k    = blockIdx.x;
    const int lane = threadIdx.x;
    const float* r = rois + k * 5;
    const int bk   = (int)r[0];

    int slot = 0, total = 0;
    for (int i = 0; i < NROI; i += 64) {
        int bi = (int)rois[(i + lane) * 5];
        unsigned long long m = __ballot(bi == bk);
        total += __popcll(m);
        int rel = k - i;
        unsigned long long lt = rel <= 0 ? 0ull
                              : (rel >= 64 ? ~0ull : ((1ull << rel) - 1ull));
        slot += __popcll(m & lt);
    }
    if (lane == 0) ((int*)(ws + CNT_OFF))[bk] = total;   // same-value dup writes ok

    if (lane < NBINS) {
        const float sw = r[1] * 0.25f - 0.5f, sh = r[2] * 0.25f - 0.5f;
        const float ew = r[3] * 0.25f - 0.5f, eh = r[4] * 0.25f - 0.5f;
        const float bh = (eh - sh) * (1.0f / 7.0f);
        const float bw = (ew - sw) * (1.0f / 7.0f);
        const int ph = (lane * 37) >> 8;        // lane/7 (exact, lane<49)
        const int pw = lane - ph * 7;
        int ylA, ylB, xl0, xl1; float lyA, lyB, lx0, lx1;
        samp_geo(sh, bh, ph, 0, ylA, lyA);
        samp_geo(sh, bh, ph, 1, ylB, lyB);
        samp_geo(sw, bw, pw, 0, xl0, lx0);
        samp_geo(sw, bw, pw, 1, xl1, lx1);
        if (xl0 >= FEAT_W - 1) lx0 = 0.0f;      // x border: xh==xl -> kill hi weight
        if (xl1 >= FEAT_W - 1) lx1 = 0.0f;      //   (OOB pair lands in zeroed pad)
        int yhA = min(ylA + 1, FEAT_H - 1), yhB = min(ylB + 1, FEAT_H - 1);
        uint4 a, b2;
        a.x  = (unsigned)(ylA * 400) | ((unsigned)(yhA * 400) << 16);  // planar byte offs
        a.y  = (unsigned)(ylB * 400) | ((unsigned)(yhB * 400) << 16);
        a.z  = (unsigned)(xl0 * 4)   | ((unsigned)(xl1 * 4)   << 16);
        a.w  = __float_as_uint(lyA);
        b2.x = __float_as_uint(lyB);
        b2.y = __float_as_uint(lx0);
        b2.z = __float_as_uint(lx1);
        b2.w = (unsigned)(k * (FEAT_C * NBINS) + lane);  // out idx (roi+bin part)
        char* dst = ws + bk * IMG_STRIDE + (slot * NBINS + lane) * REC_BYTES;
        *(uint4*)dst        = a;
        *(uint4*)(dst + 16) = b2;
    }
}

// ---- Main: block = (img, channel pair); interleaved pair-plane in LDS.
__global__ __launch_bounds__(512, 4) void roialign_main(
    const float* __restrict__ feat, const char* __restrict__ ws,
    float* __restrict__ out)
{
    __shared__ __align__(16) float s_img[2 * HW + 8];    // 80032 B -> 2 blocks/CU

    const int bid = blockIdx.x;
    const int img = bid & 3;
    const int cp  = bid >> 2;                            // channel pair 0..127
    const int tid = threadIdx.x;

    // Stage both planes interleaved: coalesced float4 loads, b128 LDS writes.
    const float* c0 = feat + (size_t)(img * FEAT_C + 2 * cp) * HW;
    const float* c1 = c0 + HW;
    for (int t = tid; t < HW / 4; t += 512) {            // 2500 float4 chunks
        float4 A = ((const float4*)c0)[t];
        float4 B = ((const float4*)c1)[t];
        ((float4*)s_img)[2 * t]     = make_float4(A.x, B.x, A.y, B.y);
        ((float4*)s_img)[2 * t + 1] = make_float4(A.z, B.z, A.w, B.w);
    }
    if (tid < 8) s_img[2 * HW + tid] = 0.0f;   // zero-weight border tap target

    int cnt = ((const int*)(ws + CNT_OFF))[img];
    const int nrec = (cnt < 0 || cnt > NROI) ? 0 : cnt * NBINS;   // poison-safe
    const char* rb = ws + img * IMG_STRIDE;
    float* const oc = out + (size_t)(2 * cp) * NBINS;

    // Prefetch record 0 while staging loads are in flight.
    int   idx = tid;
    uint4 ra, rk;
    if (idx < nrec) {
        const char* p = rb + (size_t)idx * REC_BYTES;
        ra = *(const uint4*)p;
        rk = *(const uint4*)(p + 16);
    }
    __syncthreads();                            // publishes LDS plane

    while (idx < nrec) {
        const uint4 a = ra, b2 = rk;
        const int nidx = idx + 512;
        if (nidx < nrec) {                      // prefetch next record
            const char* p = rb + (size_t)nidx * REC_BYTES;
            ra = *(const uint4*)p;
            rk = *(const uint4*)(p + 16);
        }

        const char* base = (const char*)s_img;
        // Planar byte-offsets x2 = interleaved float2 offsets.
        const int oAl = (a.x & 0xffff) * 2, oAh = (a.x >> 16) * 2;
        const int oBl = (a.y & 0xffff) * 2, oBh = (a.y >> 16) * 2;
        const int x0  = (a.z & 0xffff) * 2, x1  = (a.z >> 16) * 2;
        const float lyA = __uint_as_float(a.w),  hyA = 1.0f - lyA;
        const float lyB = __uint_as_float(rk.x == rk.x ? b2.x : b2.x), hyB = 1.0f - __uint_as_float(b2.x);
        const float lx0 = __uint_as_float(b2.y), hx0 = 1.0f - lx0;
        const float lx1 = __uint_as_float(b2.z), hx1 = 1.0f - lx1;

        // 8 ds_read2_b64: each serves BOTH channels (adjacent f32x2 pair).
        const f32x2* pAl0 = (const f32x2*)(base + oAl + x0);
        const f32x2* pAl1 = (const f32x2*)(base + oAl + x1);
        const f32x2* pAh0 = (const f32x2*)(base + oAh + x0);
        const f32x2* pAh1 = (const f32x2*)(base + oAh + x1);
        const f32x2* pBl0 = (const f32x2*)(base + oBl + x0);
        const f32x2* pBl1 = (const f32x2*)(base + oBl + x1);
        const f32x2* pBh0 = (const f32x2*)(base + oBh + x0);
        const f32x2* pBh1 = (const f32x2*)(base + oBh + x1);

        f32x2 sAl = pAl0[0] * hx0 + pAl0[1] * lx0 + pAl1[0] * hx1 + pAl1[1] * lx1;
        f32x2 sAh = pAh0[0] * hx0 + pAh0[1] * lx0 + pAh1[0] * hx1 + pAh1[1] * lx1;
        f32x2 sBl = pBl0[0] * hx0 + pBl0[1] * lx0 + pBl1[0] * hx1 + pBl1[1] * lx1;
        f32x2 sBh = pBh0[0] * hx0 + pBh0[1] * lx0 + pBh1[0] * hx1 + pBh1[1] * lx1;
        f32x2 acc = (sAl * hyA + sAh * lyA + sBl * hyB + sBh * __uint_as_float(b2.x)) * 0.25f;

        float* o = oc + b2.w;
        o[0]     = acc.x;                       // channel 2cp
        o[NBINS] = acc.y;                       // channel 2cp+1
        idx = nidx;
    }
}

extern "C" void kernel_launch(void* const* d_in, const int* in_sizes, int n_in,
                              void* d_out, int out_size, void* d_ws, size_t ws_size,
                              hipStream_t stream) {
    const float* feat = (const float*)d_in[0];
    const float* rois = (const float*)d_in[1];
    float*       outp = (float*)d_out;
    roialign_setup<<<dim3(NROI), dim3(64), 0, stream>>>(rois, (char*)d_ws);
    roialign_main<<<dim3(IMG_N * (FEAT_C / 2)), dim3(512), 0, stream>>>(
        feat, (const char*)d_ws, outp);
}